// Round 1
// baseline (326.747 us; speedup 1.0000x reference)
//
#include <hip/hip_runtime.h>
#include <math.h>

// Problem constants
#define NBATCH 4096      // BS*T
#define NAG    16        // N agents
#define UDIM   32
#define SDIM   560
#define HN     4
#define EDIM   32
#define GHD    64
#define WCOLS  192       // 128 sel + 32 V-hidden + 4 wh + 28 pad
#define NEGV   -99999999.0f
#define COEF   0.001f

// workspace layout (float offsets)
#define WS_WCAT  0                          // [560][192] transposed weight panel
#define WS_W1T   (SDIM*WCOLS)               // [64][64]  g_W1 transposed
#define WS_P     (WS_W1T + 64*64)           // [4096][192] per-row projections
#define WS_PART  (WS_P + NBATCH*WCOLS)      // [4096][8] partial sums (sumsq, ent[4])

// ---------------------------------------------------------------------------
// k0: build transposed weight panel WcatT[s][c] and W1T[k][g]
//   c <128  -> sel_W[c][s]   (sel rows, he-major)
//   c 128.. -> V_W1[c-128][s]
//   c 160.. -> wh_W[c-160][s]
//   else 0
__global__ void k0_prep(const float* __restrict__ sel_W,
                        const float* __restrict__ V_W1,
                        const float* __restrict__ wh_W,
                        const float* __restrict__ g_W1,
                        float* __restrict__ ws) {
    int idx = blockIdx.x * 256 + threadIdx.x;
    if (idx < SDIM * WCOLS) {
        int s = idx / WCOLS, c = idx - s * WCOLS;
        float v = 0.f;
        if (c < 128)      v = sel_W[c * SDIM + s];
        else if (c < 160) v = V_W1[(c - 128) * SDIM + s];
        else if (c < 164) v = wh_W[(c - 160) * SDIM + s];
        ws[WS_WCAT + idx] = v;
    } else {
        int i2 = idx - SDIM * WCOLS;
        if (i2 < 64 * 64) {
            int k = i2 >> 6, g = i2 & 63;
            ws[WS_W1T + i2] = g_W1[g * 64 + k];   // W1T[k][g]
        }
    }
}

// ---------------------------------------------------------------------------
// k1: P[4096][192] = states[4096][560] @ WcatT   (skinny GEMM, 16-row tiles)
#define K1_ROWS 16
#define K1_KC   56
__global__ __launch_bounds__(256) void k1_gemm(const float* __restrict__ states,
                                               const float* __restrict__ ws,
                                               float* __restrict__ wsP) {
    __shared__ float As[K1_ROWS][K1_KC + 1];              // +1 pad: bank-safe
    __shared__ __align__(16) float Bs[K1_KC * WCOLS];     // 43 KB
    const float* wcatT = &ws[WS_WCAT];
    int tid = threadIdx.x;
    int b0  = blockIdx.x * K1_ROWS;
    int r   = tid >> 4;       // 0..15 row
    int cg  = tid & 15;       // 0..15 col group (12 cols each)
    float acc[12];
#pragma unroll
    for (int j = 0; j < 12; ++j) acc[j] = 0.f;

    for (int ks = 0; ks < SDIM; ks += K1_KC) {
        {   // stage A tile: 16 rows x 56
            int rr = tid >> 4, kk = tid & 15;
            for (int k2 = kk; k2 < K1_KC; k2 += 16)
                As[rr][k2] = states[(b0 + rr) * SDIM + ks + k2];
        }
        // stage B tile: contiguous 56*192 floats, float4 loads
        for (int i = tid * 4; i < K1_KC * WCOLS; i += 256 * 4) {
            float4 v = *reinterpret_cast<const float4*>(&wcatT[ks * WCOLS + i]);
            *reinterpret_cast<float4*>(&Bs[i]) = v;
        }
        __syncthreads();
#pragma unroll 4
        for (int kk = 0; kk < K1_KC; ++kk) {
            float a = As[r][kk];
            const float* bp = &Bs[kk * WCOLS + cg * 12];
#pragma unroll
            for (int j = 0; j < 12; ++j) acc[j] += a * bp[j];
        }
        __syncthreads();
    }
    float* outp = &wsP[WS_P + (b0 + r) * WCOLS + cg * 12];
#pragma unroll
    for (int j = 0; j < 12; ++j) outp[j] = acc[j];
}

// ---------------------------------------------------------------------------
// k2: one block per batch row. proj/logits/softmax, graph MLP, adjacency,
//     renorm, q_tot, adj output, partial sums for scalars.
__global__ __launch_bounds__(256) void k2_main(
    const float* __restrict__ agent_qs,
    const float* __restrict__ states,
    const int*   __restrict__ actions,
    const float* __restrict__ key_W,
    const float* __restrict__ wh_b,
    const float* __restrict__ V_b1,
    const float* __restrict__ V_W2,
    const float* __restrict__ V_b2,
    const float* __restrict__ g_b1,
    const float* __restrict__ g_W2,
    const float* __restrict__ g_b2,
    const float* __restrict__ g_W3,
    const float* __restrict__ g_b3,
    float* __restrict__ ws,
    float* __restrict__ out)
{
    const int b   = blockIdx.x;
    const int tid = threadIdx.x;

    __shared__ __align__(16) float W2s[GHD * GHD];   // 16 KB
    __shared__ float unit_s[NAG * 33];               // padded stride 33
    __shared__ float sel_s[128];
    __shared__ float proj_s[HN * 33];
    __shared__ float attw_s[64];
    __shared__ float As[NAG * 68];                   // padded stride 68
    __shared__ float Bsh[NAG * 68];
    __shared__ float W3s[GHD], b2s[GHD], b1s[GHD];
    __shared__ float adjmean_s[NAG];
    __shared__ float qs_s[NAG];
    __shared__ float red_s[256];

    // ---- stage
    for (int i4 = tid; i4 < GHD * GHD / 4; i4 += 256)
        reinterpret_cast<float4*>(W2s)[i4] = reinterpret_cast<const float4*>(g_W2)[i4];
    for (int i = tid; i < NAG * UDIM; i += 256)
        unit_s[(i >> 5) * 33 + (i & 31)] = states[b * SDIM + i];
    if (tid < 128) sel_s[tid] = ws[WS_P + b * WCOLS + tid];
    if (tid < GHD) { W3s[tid] = g_W3[tid]; b2s[tid] = g_b2[tid]; b1s[tid] = g_b1[tid]; }
    if (tid < NAG) qs_s[tid] = agent_qs[b * NAG + tid];
    __syncthreads();

    // ---- proj[h][u] = sum_e sel[h,e] * key_W[h,e,u]
    if (tid < 128) {
        int h = tid >> 5, u = tid & 31;
        float a = 0.f;
#pragma unroll
        for (int e = 0; e < EDIM; ++e)
            a += sel_s[h * EDIM + e] * key_W[(h * EDIM + e) * UDIM + u];
        proj_s[h * 33 + u] = a;
    }
    // ---- A[i][g] = u_i . W1a[g] + b1[g] ;  B[j][g] = u_j . W1b[g]
    {
        const float* W1T = &ws[WS_W1T];
        for (int o = tid; o < 2 * NAG * GHD; o += 256) {
            int which = o >> 10;          // 0=A, 1=B
            int i = (o >> 6) & 15;
            int g = o & 63;
            float a = 0.f;
#pragma unroll
            for (int u = 0; u < UDIM; ++u)
                a += unit_s[i * 33 + u] * W1T[(which * UDIM + u) * 64 + g];
            if (which == 0) As[i * 68 + g] = a + b1s[g];
            else            Bsh[i * 68 + g] = a;
        }
    }
    __syncthreads();

    // ---- wave 0: logits + reg sumsq + masked softmax
    if (tid < 64) {
        int n = tid & 15;
        int h = tid >> 4;
        float l = 0.f;
#pragma unroll
        for (int u = 0; u < UDIM; ++u)
            l += proj_s[h * 33 + u] * unit_s[n * 33 + u];
        float sq = l * l;
#pragma unroll
        for (int m = 1; m < 64; m <<= 1) sq += __shfl_xor(sq, m, 64);
        if (tid == 0) ws[WS_PART + b * 8 + 0] = sq;
        float sc = l * 0.17677669529663688f;          // 1/sqrt(32)
        if (actions[b * NAG + n] == 0) sc = NEGV;
        float mx = sc;
#pragma unroll
        for (int m = 1; m < 16; m <<= 1) mx = fmaxf(mx, __shfl_xor(mx, m, 16));
        float ex = expf(sc - mx);
        float sm = ex;
#pragma unroll
        for (int m = 1; m < 16; m <<= 1) sm += __shfl_xor(sm, m, 16);
        attw_s[tid] = ex / sm;
    }

    // ---- pair loop: one (i,j) per thread
    {
        int i = tid >> 4, j = tid & 15;
        float h1[GHD];
#pragma unroll
        for (int g = 0; g < GHD; ++g)
            h1[g] = fmaxf(As[i * 68 + g] + Bsh[j * 68 + g], 0.f);
        float el = g_b3[0];
        for (int g2 = 0; g2 < GHD; ++g2) {
            float a = b2s[g2];
#pragma unroll
            for (int g = 0; g < GHD; ++g)
                a += h1[g] * W2s[g2 * GHD + g];
            el += fmaxf(a, 0.f) * W3s[g2];
        }
        float adjv = 1.f / (1.f + expf(-el));
        if (i == j) adjv += 1.f;
        out[4101 + b * 256 + tid] = adjv;   // adj output
        red_s[tid] = adjv;
    }
    __syncthreads();

    // ---- adj_mean[j] = mean_i adj[i][j]
    if (tid < NAG) {
        float s = 0.f;
#pragma unroll
        for (int i = 0; i < NAG; ++i) s += red_s[i * NAG + tid];
        adjmean_s[tid] = s * (1.0f / 16.0f);
    }
    __syncthreads();

    // ---- renorm, head_q, entropy, q_tot pieces
    if (tid < 64) {
        int n = tid & 15;
        int h = tid >> 4;
        float a = attw_s[tid] * adjmean_s[n];
        float s = a;
#pragma unroll
        for (int m = 1; m < 16; m <<= 1) s += __shfl_xor(s, m, 16);
        float adjw = a / (s + 1e-8f);
        float hq  = qs_s[n] * adjw;
        float ent = -logf(adjw + 1e-8f) * adjw;
#pragma unroll
        for (int m = 1; m < 16; m <<= 1) {
            hq  += __shfl_xor(hq, m, 16);
            ent += __shfl_xor(ent, m, 16);
        }
        if (n == 0) {
            float wh = fabsf(ws[WS_P + b * WCOLS + 160 + h] + wh_b[h]);
            red_s[h] = wh * hq;
            ws[WS_PART + b * 8 + 1 + h] = ent;
        }
    }
    __syncthreads();
    if (tid == 0) {
        float v = V_b2[0];
#pragma unroll
        for (int e = 0; e < EDIM; ++e)
            v += fmaxf(ws[WS_P + b * WCOLS + 128 + e] + V_b1[e], 0.f) * V_W2[e];
        out[b] = red_s[0] + red_s[1] + red_s[2] + red_s[3] + v;
    }
}

// ---------------------------------------------------------------------------
// k3: deterministic final reduction of partials -> attend_mag_regs, head_entropies
__global__ __launch_bounds__(256) void k3_final(const float* __restrict__ ws,
                                                float* __restrict__ out) {
    __shared__ float red[4][5];
    int tid = threadIdx.x;
    float acc[5] = {0.f, 0.f, 0.f, 0.f, 0.f};
    for (int r = tid; r < NBATCH; r += 256) {
        const float* p = &ws[WS_PART + r * 8];
#pragma unroll
        for (int j = 0; j < 5; ++j) acc[j] += p[j];
    }
#pragma unroll
    for (int j = 0; j < 5; ++j) {
        float v = acc[j];
#pragma unroll
        for (int m = 1; m < 64; m <<= 1) v += __shfl_xor(v, m, 64);
        if ((tid & 63) == 0) red[tid >> 6][j] = v;
    }
    __syncthreads();
    if (tid == 0) {
        float s0 = red[0][0] + red[1][0] + red[2][0] + red[3][0];
        out[4096] = s0 * (COEF / 65536.0f);          // mean over B*N, sum over H
#pragma unroll
        for (int h = 0; h < 4; ++h) {
            float s = red[0][1 + h] + red[1][1 + h] + red[2][1 + h] + red[3][1 + h];
            out[4097 + h] = s * (1.0f / 4096.0f);    // mean over B
        }
    }
}

// ---------------------------------------------------------------------------
extern "C" void kernel_launch(void* const* d_in, const int* in_sizes, int n_in,
                              void* d_out, int out_size, void* d_ws, size_t ws_size,
                              hipStream_t stream) {
    const float* agent_qs = (const float*)d_in[0];
    const float* states   = (const float*)d_in[1];
    const int*   actions  = (const int*)  d_in[2];
    const float* sel_W    = (const float*)d_in[3];
    const float* key_W    = (const float*)d_in[4];
    const float* wh_W     = (const float*)d_in[5];
    const float* wh_b     = (const float*)d_in[6];
    const float* V_W1     = (const float*)d_in[7];
    const float* V_b1     = (const float*)d_in[8];
    const float* V_W2     = (const float*)d_in[9];
    const float* V_b2     = (const float*)d_in[10];
    const float* g_W1     = (const float*)d_in[11];
    const float* g_b1     = (const float*)d_in[12];
    const float* g_W2     = (const float*)d_in[13];
    const float* g_b2     = (const float*)d_in[14];
    const float* g_W3     = (const float*)d_in[15];
    const float* g_b3     = (const float*)d_in[16];

    float* ws  = (float*)d_ws;
    float* out = (float*)d_out;

    // k0: weight transposes (111,616 elements)
    k0_prep<<<436, 256, 0, stream>>>(sel_W, V_W1, wh_W, g_W1, ws);
    // k1: skinny GEMM [4096,560]x[560,192]
    k1_gemm<<<NBATCH / K1_ROWS, 256, 0, stream>>>(states, ws, ws);
    // k2: per-row fused mixer + graph MLP
    k2_main<<<NBATCH, 256, 0, stream>>>(agent_qs, states, actions, key_W,
                                        wh_b, V_b1, V_W2, V_b2,
                                        g_b1, g_W2, g_b2, g_W3, g_b3,
                                        ws, out);
    // k3: scalar outputs
    k3_final<<<1, 256, 0, stream>>>(ws, out);
}

// Round 6
// 307.500 us; speedup vs baseline: 1.0626x; 1.0626x over previous
//
#include <hip/hip_runtime.h>
#include <math.h>

// Problem constants
#define NBATCH 4096      // BS*T
#define NAG    16        // N agents
#define UDIM   32
#define SDIM   560
#define HN     4
#define EDIM   32
#define GHD    64
#define WCOLS  192       // 128 sel + 32 V-hidden + 4 wh + 28 pad
#define NEGV   -99999999.0f
#define COEF   0.001f

// workspace layout (float offsets)
#define WS_WCAT  0                          // [560][192] transposed weight panel
#define WS_W1T   (SDIM*WCOLS)               // [64][64]  g_W1 transposed
#define WS_P     (WS_W1T + 64*64)           // [4096][192] per-row projections
#define WS_PART  (WS_P + NBATCH*WCOLS)      // [4096][8] partial sums (sumsq, ent[4])

// ---------------------------------------------------------------------------
// k0: build transposed weight panel WcatT[s][c] and W1T[k][g]
__global__ void k0_prep(const float* __restrict__ sel_W,
                        const float* __restrict__ V_W1,
                        const float* __restrict__ wh_W,
                        const float* __restrict__ g_W1,
                        float* __restrict__ ws) {
    int idx = blockIdx.x * 256 + threadIdx.x;
    if (idx < SDIM * WCOLS) {
        int s = idx / WCOLS, c = idx - s * WCOLS;
        float v = 0.f;
        if (c < 128)      v = sel_W[c * SDIM + s];
        else if (c < 160) v = V_W1[(c - 128) * SDIM + s];
        else if (c < 164) v = wh_W[(c - 160) * SDIM + s];
        ws[WS_WCAT + idx] = v;
    } else {
        int i2 = idx - SDIM * WCOLS;
        if (i2 < 64 * 64) {
            int k = i2 >> 6, g = i2 & 63;
            ws[WS_W1T + i2] = g_W1[g * 64 + k];   // W1T[k][g]
        }
    }
}

// ---------------------------------------------------------------------------
// k1: P[4096][192] = states[4096][560] @ WcatT   (skinny GEMM, 16-row tiles)
#define K1_ROWS 16
#define K1_KC   56
__global__ __launch_bounds__(256) void k1_gemm(const float* __restrict__ states,
                                               const float* __restrict__ ws,
                                               float* __restrict__ wsP) {
    __shared__ float As[K1_ROWS][K1_KC + 1];              // +1 pad: bank-safe
    __shared__ __align__(16) float Bs[K1_KC * WCOLS];     // 43 KB
    const float* wcatT = &ws[WS_WCAT];
    int tid = threadIdx.x;
    int b0  = blockIdx.x * K1_ROWS;
    int r   = tid >> 4;       // 0..15 row
    int cg  = tid & 15;       // 0..15 col group (12 cols each)
    float acc[12];
#pragma unroll
    for (int j = 0; j < 12; ++j) acc[j] = 0.f;

    for (int ks = 0; ks < SDIM; ks += K1_KC) {
        {   // stage A tile: 16 rows x 56
            int rr = tid >> 4, kk = tid & 15;
            for (int k2 = kk; k2 < K1_KC; k2 += 16)
                As[rr][k2] = states[(b0 + rr) * SDIM + ks + k2];
        }
        // stage B tile: contiguous 56*192 floats, float4 loads
        for (int i = tid * 4; i < K1_KC * WCOLS; i += 256 * 4) {
            float4 v = *reinterpret_cast<const float4*>(&wcatT[ks * WCOLS + i]);
            *reinterpret_cast<float4*>(&Bs[i]) = v;
        }
        __syncthreads();
#pragma unroll 4
        for (int kk = 0; kk < K1_KC; ++kk) {
            float a = As[r][kk];
            const float* bp = &Bs[kk * WCOLS + cg * 12];
#pragma unroll
            for (int j = 0; j < 12; ++j) acc[j] += a * bp[j];
        }
        __syncthreads();
    }
    float* outp = &wsP[WS_P + (b0 + r) * WCOLS + cg * 12];
#pragma unroll
    for (int j = 0; j < 12; ++j) outp[j] = acc[j];
}

// ---------------------------------------------------------------------------
// k2: one block per batch row. proj/logits/softmax, graph MLP, adjacency,
//     renorm, q_tot, adj output, partial sums for scalars.
// v2: h1 held in 64 VGPRs (float4 x16); W2/b2/W3 read via wave-uniform global
//     loads (scalarize to s_load, SMEM pipe parallel to VALU); W2s LDS dropped.
__global__ __launch_bounds__(256, 4) void k2_main(
    const float* __restrict__ agent_qs,
    const float* __restrict__ states,
    const int*   __restrict__ actions,
    const float* __restrict__ key_W,
    const float* __restrict__ wh_b,
    const float* __restrict__ V_b1,
    const float* __restrict__ V_W2,
    const float* __restrict__ V_b2,
    const float* __restrict__ g_b1,
    const float* __restrict__ g_W2,
    const float* __restrict__ g_b2,
    const float* __restrict__ g_W3,
    const float* __restrict__ g_b3,
    float* __restrict__ ws,
    float* __restrict__ out)
{
    const int b   = blockIdx.x;
    const int tid = threadIdx.x;

    __shared__ float unit_s[NAG * 33];               // padded stride 33
    __shared__ float sel_s[128];
    __shared__ float proj_s[HN * 33];
    __shared__ float attw_s[64];
    __shared__ __align__(16) float As[NAG * 68];     // stride 68 floats (16B ok)
    __shared__ __align__(16) float Bsh[NAG * 68];
    __shared__ float b1s[GHD];
    __shared__ float adjmean_s[NAG];
    __shared__ float qs_s[NAG];
    __shared__ float red_s[256];

    // ---- stage
    for (int i = tid; i < NAG * UDIM; i += 256)
        unit_s[(i >> 5) * 33 + (i & 31)] = states[b * SDIM + i];
    if (tid < 128) sel_s[tid] = ws[WS_P + b * WCOLS + tid];
    if (tid < GHD) b1s[tid] = g_b1[tid];
    if (tid < NAG) qs_s[tid] = agent_qs[b * NAG + tid];
    __syncthreads();

    // ---- proj[h][u] = sum_e sel[h,e] * key_W[h,e,u]
    if (tid < 128) {
        int h = tid >> 5, u = tid & 31;
        float a = 0.f;
#pragma unroll
        for (int e = 0; e < EDIM; ++e)
            a += sel_s[h * EDIM + e] * key_W[(h * EDIM + e) * UDIM + u];
        proj_s[h * 33 + u] = a;
    }
    // ---- A[i][g] = u_i . W1a[g] + b1[g] ;  B[j][g] = u_j . W1b[g]
    {
        const float* W1T = &ws[WS_W1T];
        for (int o = tid; o < 2 * NAG * GHD; o += 256) {
            int which = o >> 10;          // 0=A, 1=B
            int i = (o >> 6) & 15;
            int g = o & 63;
            float a = 0.f;
#pragma unroll
            for (int u = 0; u < UDIM; ++u)
                a += unit_s[i * 33 + u] * W1T[(which * UDIM + u) * 64 + g];
            if (which == 0) As[i * 68 + g] = a + b1s[g];
            else            Bsh[i * 68 + g] = a;
        }
    }
    __syncthreads();

    // ---- wave 0: logits + reg sumsq + masked softmax
    if (tid < 64) {
        int n = tid & 15;
        int h = tid >> 4;
        float l = 0.f;
#pragma unroll
        for (int u = 0; u < UDIM; ++u)
            l += proj_s[h * 33 + u] * unit_s[n * 33 + u];
        float sq = l * l;
#pragma unroll
        for (int m = 1; m < 64; m <<= 1) sq += __shfl_xor(sq, m, 64);
        if (tid == 0) ws[WS_PART + b * 8 + 0] = sq;
        float sc = l * 0.17677669529663688f;          // 1/sqrt(32)
        if (actions[b * NAG + n] == 0) sc = NEGV;
        float mx = sc;
#pragma unroll
        for (int m = 1; m < 16; m <<= 1) mx = fmaxf(mx, __shfl_xor(mx, m, 16));
        float ex = expf(sc - mx);
        float sm = ex;
#pragma unroll
        for (int m = 1; m < 16; m <<= 1) sm += __shfl_xor(sm, m, 16);
        attw_s[tid] = ex / sm;
    }

    // ---- pair loop: one (i,j) per thread; h1 in registers
    {
        int i = tid >> 4, j = tid & 15;
        const float4* Ap = reinterpret_cast<const float4*>(&As[i * 68]);
        const float4* Bp = reinterpret_cast<const float4*>(&Bsh[j * 68]);
        float4 h1v[16];
#pragma unroll
        for (int q = 0; q < 16; ++q) {
            float4 av = Ap[q], bv = Bp[q];
            h1v[q].x = fmaxf(av.x + bv.x, 0.f);
            h1v[q].y = fmaxf(av.y + bv.y, 0.f);
            h1v[q].z = fmaxf(av.z + bv.z, 0.f);
            h1v[q].w = fmaxf(av.w + bv.w, 0.f);
        }
        float el = g_b3[0];
#pragma unroll 2
        for (int g2 = 0; g2 < GHD; ++g2) {
            const float* w = &g_W2[g2 * GHD];   // wave-uniform -> s_load
            float a0 = 0.f, a1 = 0.f, a2 = 0.f, a3 = 0.f;
#pragma unroll
            for (int q = 0; q < 16; ++q) {
                a0 += h1v[q].x * w[q * 4 + 0];
                a1 += h1v[q].y * w[q * 4 + 1];
                a2 += h1v[q].z * w[q * 4 + 2];
                a3 += h1v[q].w * w[q * 4 + 3];
            }
            float a = ((a0 + a1) + (a2 + a3)) + g_b2[g2];
            el += fmaxf(a, 0.f) * g_W3[g2];
        }
        float adjv = 1.f / (1.f + expf(-el));
        if (i == j) adjv += 1.f;
        out[4101 + b * 256 + tid] = adjv;   // adj output
        red_s[tid] = adjv;
    }
    __syncthreads();

    // ---- adj_mean[j] = mean_i adj[i][j]
    if (tid < NAG) {
        float s = 0.f;
#pragma unroll
        for (int i = 0; i < NAG; ++i) s += red_s[i * NAG + tid];
        adjmean_s[tid] = s * (1.0f / 16.0f);
    }
    __syncthreads();

    // ---- renorm, head_q, entropy, q_tot pieces
    if (tid < 64) {
        int n = tid & 15;
        int h = tid >> 4;
        float a = attw_s[tid] * adjmean_s[n];
        float s = a;
#pragma unroll
        for (int m = 1; m < 16; m <<= 1) s += __shfl_xor(s, m, 16);
        float adjw = a / (s + 1e-8f);
        float hq  = qs_s[n] * adjw;
        float ent = -logf(adjw + 1e-8f) * adjw;
#pragma unroll
        for (int m = 1; m < 16; m <<= 1) {
            hq  += __shfl_xor(hq, m, 16);
            ent += __shfl_xor(ent, m, 16);
        }
        if (n == 0) {
            float wh = fabsf(ws[WS_P + b * WCOLS + 160 + h] + wh_b[h]);
            red_s[h] = wh * hq;
            ws[WS_PART + b * 8 + 1 + h] = ent;
        }
    }
    __syncthreads();
    if (tid == 0) {
        float v = V_b2[0];
#pragma unroll
        for (int e = 0; e < EDIM; ++e)
            v += fmaxf(ws[WS_P + b * WCOLS + 128 + e] + V_b1[e], 0.f) * V_W2[e];
        out[b] = red_s[0] + red_s[1] + red_s[2] + red_s[3] + v;
    }
}

// ---------------------------------------------------------------------------
// k3: deterministic final reduction of partials -> attend_mag_regs, head_entropies
__global__ __launch_bounds__(256) void k3_final(const float* __restrict__ ws,
                                                float* __restrict__ out) {
    __shared__ float red[4][5];
    int tid = threadIdx.x;
    float acc[5] = {0.f, 0.f, 0.f, 0.f, 0.f};
    for (int r = tid; r < NBATCH; r += 256) {
        const float* p = &ws[WS_PART + r * 8];
#pragma unroll
        for (int j = 0; j < 5; ++j) acc[j] += p[j];
    }
#pragma unroll
    for (int j = 0; j < 5; ++j) {
        float v = acc[j];
#pragma unroll
        for (int m = 1; m < 64; m <<= 1) v += __shfl_xor(v, m, 64);
        if ((tid & 63) == 0) red[tid >> 6][j] = v;
    }
    __syncthreads();
    if (tid == 0) {
        float s0 = red[0][0] + red[1][0] + red[2][0] + red[3][0];
        out[4096] = s0 * (COEF / 65536.0f);          // mean over B*N, sum over H
#pragma unroll
        for (int h = 0; h < 4; ++h) {
            float s = red[0][1 + h] + red[1][1 + h] + red[2][1 + h] + red[3][1 + h];
            out[4097 + h] = s * (1.0f / 4096.0f);    // mean over B
        }
    }
}

// ---------------------------------------------------------------------------
extern "C" void kernel_launch(void* const* d_in, const int* in_sizes, int n_in,
                              void* d_out, int out_size, void* d_ws, size_t ws_size,
                              hipStream_t stream) {
    const float* agent_qs = (const float*)d_in[0];
    const float* states   = (const float*)d_in[1];
    const int*   actions  = (const int*)  d_in[2];
    const float* sel_W    = (const float*)d_in[3];
    const float* key_W    = (const float*)d_in[4];
    const float* wh_W     = (const float*)d_in[5];
    const float* wh_b     = (const float*)d_in[6];
    const float* V_W1     = (const float*)d_in[7];
    const float* V_b1     = (const float*)d_in[8];
    const float* V_W2     = (const float*)d_in[9];
    const float* V_b2     = (const float*)d_in[10];
    const float* g_W1     = (const float*)d_in[11];
    const float* g_b1     = (const float*)d_in[12];
    const float* g_W2     = (const float*)d_in[13];
    const float* g_b2     = (const float*)d_in[14];
    const float* g_W3     = (const float*)d_in[15];
    const float* g_b3     = (const float*)d_in[16];

    float* ws  = (float*)d_ws;
    float* out = (float*)d_out;

    // k0: weight transposes (111,616 elements)
    k0_prep<<<436, 256, 0, stream>>>(sel_W, V_W1, wh_W, g_W1, ws);
    // k1: skinny GEMM [4096,560]x[560,192]
    k1_gemm<<<NBATCH / K1_ROWS, 256, 0, stream>>>(states, ws, ws);
    // k2: per-row fused mixer + graph MLP
    k2_main<<<NBATCH, 256, 0, stream>>>(agent_qs, states, actions, key_W,
                                        wh_b, V_b1, V_W2, V_b2,
                                        g_b1, g_W2, g_b2, g_W3, g_b3,
                                        ws, out);
    // k3: scalar outputs
    k3_final<<<1, 256, 0, stream>>>(ws, out);
}